// Round 1
// baseline (593.517 us; speedup 1.0000x reference)
//
#include <hip/hip_runtime.h>
#include <math.h>

// Problem constants (B=4, L=4096, n=4, C=1024) — all tensors fp32
#define DTOT   4096          // n*C
#define NTOK   16384         // B*L
#define NJ     24            // 4 pre + 4 post + 16 res dot products
#define NG     25            // NJ dots + sumsq
#define DC     256           // d-elements per chunk in dots kernel
#define NCHUNK (DTOT / DC)   // 16
#define TOKB   256           // tokens per dots-block (256 threads x 1 token)

// ---------------------------------------------------------------------------
// Kernel 0: Wt[d][j] = W[j][d] * norm_w[d], j: 0-3 pre, 4-7 post, 8-23 res
// ---------------------------------------------------------------------------
__global__ void prep_kernel(const float* __restrict__ Wpre,
                            const float* __restrict__ Wpost,
                            const float* __restrict__ Wres,
                            const float* __restrict__ nw,
                            float* __restrict__ Wt) {
    int i = blockIdx.x * 256 + threadIdx.x;   // over 4096*24
    if (i >= DTOT * NJ) return;
    int d = i / NJ;
    int j = i - d * NJ;
    float w;
    if (j < 4)       w = Wpre [(size_t)j       * DTOT + d];
    else if (j < 8)  w = Wpost[(size_t)(j - 4) * DTOT + d];
    else             w = Wres [(size_t)(j - 8) * DTOT + d];
    Wt[i] = w * nw[d];
}

// ---------------------------------------------------------------------------
// Kernel 1: partial dots + sumsq per (token, d-chunk).
// grid = (NTOK/TOKB, NCHUNK) = 64 x 16 -> 1024 blocks (4 blocks/CU, 16 waves/CU
// for latency hiding; was 512 blocks = 2 waves/SIMD, latency-starved).
// Each thread: 1 token, full 256-element chunk, 25 accumulators.
// Gpart layout: [chunk][j(0..24)][token]  (coalesced stores across lanes)
// ---------------------------------------------------------------------------
__global__ __launch_bounds__(256) void dots_kernel(
        const float* __restrict__ x,
        const float* __restrict__ Wt,
        float* __restrict__ Gpart) {
    __shared__ float wlds[DC * NJ];   // 256*24*4 = 24576 B

    const int tid = threadIdx.x;
    const int tg  = blockIdx.x;       // token group (0..63)
    const int ch  = blockIdx.y;       // d chunk (0..15)

    // Stage this chunk's weights into LDS (flat float4 copy; base 16B aligned)
    {
        const float4* src = (const float4*)(Wt + (size_t)ch * DC * NJ);
        float4* dst = (float4*)wlds;
        #pragma unroll
        for (int i = 0; i < (DC * NJ / 4) / 256; ++i)   // 6 iterations
            dst[tid + 256 * i] = src[tid + 256 * i];
    }
    __syncthreads();

    const int tok = tg * TOKB + tid;
    const float4* __restrict__ x0 =
        (const float4*)(x + (size_t)tok * DTOT + (size_t)ch * DC);

    float acc[NG];
    #pragma unroll
    for (int j = 0; j < NG; ++j) acc[j] = 0.f;

    for (int dd4 = 0; dd4 < DC / 4; ++dd4) {
        float4 r = x0[dd4];
        float a[4] = { r.x, r.y, r.z, r.w };
        #pragma unroll
        for (int k = 0; k < 4; ++k) {
            const float xa = a[k];
            // 96 B row, 16B aligned: read as 6 x float4 (ds_read_b128 broadcast)
            const float4* __restrict__ wv =
                (const float4*)(wlds + (dd4 * 4 + k) * NJ);
            #pragma unroll
            for (int jv = 0; jv < 6; ++jv) {
                const float4 w = wv[jv];
                acc[4*jv+0] += xa * w.x;
                acc[4*jv+1] += xa * w.y;
                acc[4*jv+2] += xa * w.z;
                acc[4*jv+3] += xa * w.w;
            }
            acc[NG-1] += xa * xa;
        }
    }

    float* gp = Gpart + (size_t)ch * NG * NTOK;
    #pragma unroll
    for (int j = 0; j < NG; ++j)
        gp[(size_t)j * NTOK + tok] = acc[j];
}

// ---------------------------------------------------------------------------
// Kernel 2: wave-per-token, barrier-free.
// grid = NTOK/4 blocks of 256 threads; wave w handles token = 4*blk + w.
// Lanes 0..24 reduce Gpart chunks; __shfl all-gather; ALL lanes compute
// gates + Cayley redundantly (no serial section, no __syncthreads);
// each lane then produces 64 output channels (4 float4 per n-row quadrant).
// ---------------------------------------------------------------------------
__global__ __launch_bounds__(256) void out_kernel(
        const float* __restrict__ x,
        const float* __restrict__ Gpart,
        const float* __restrict__ bpre,
        const float* __restrict__ bpost,
        const float* __restrict__ bres,
        const float* __restrict__ apre,
        const float* __restrict__ apost,
        const float* __restrict__ ares,
        float* __restrict__ out) {
    const int lane  = threadIdx.x & 63;
    const int token = blockIdx.x * 4 + (threadIdx.x >> 6);

    // Phase 1: per-gate chunk reduction (lanes 0..24 active, 16 indep loads)
    float s = 0.f;
    if (lane < NG) {
        const float* gp = Gpart + (size_t)lane * NTOK + token;
        #pragma unroll
        for (int c = 0; c < NCHUNK; ++c)
            s += gp[(size_t)c * NG * NTOK];
    }

    // All-gather the 25 sums to every lane (wave-wide, no LDS, no barrier)
    float g[NG];
    #pragma unroll
    for (int j = 0; j < NG; ++j) g[j] = __shfl(s, j, 64);

    // Phase 2: gates + Cayley — computed redundantly by all 64 lanes
    const float inv = rsqrtf(g[NG-1] * (1.0f / DTOT) + 1e-6f);
    const float a_pre  = apre[0];
    const float a_post = apost[0];
    const float a_res  = ares[0];

    float hpre[4], hpost[4];
    #pragma unroll
    for (int i = 0; i < 4; ++i) {
        float z1 = a_pre  * g[i]     * inv + bpre[i];
        hpre[i]  = 1.f / (1.f + expf(-z1));
        float z2 = a_post * g[4 + i] * inv + bpost[i];
        hpost[i] = 2.f / (1.f + expf(-z2));
    }

    float M[4][4];
    #pragma unroll
    for (int i = 0; i < 4; ++i)
        #pragma unroll
        for (int j = 0; j < 4; ++j)
            M[i][j] = a_res * g[8 + i * 4 + j] * inv + bres[i * 4 + j];

    // Cayley: Q = (I - S)^{-1} (I + S), S = 0.5 (M - M^T)
    float A[4][8];
    #pragma unroll
    for (int i = 0; i < 4; ++i)
        #pragma unroll
        for (int j = 0; j < 4; ++j) {
            float S = 0.5f * (M[i][j] - M[j][i]);
            float I = (i == j) ? 1.f : 0.f;
            A[i][j]     = I - S;
            A[i][4 + j] = I + S;
        }
    // Gauss-Jordan; (I - S) with small skew S is diag-dominant, no pivoting
    #pragma unroll
    for (int k = 0; k < 4; ++k) {
        float pv = 1.f / A[k][k];
        #pragma unroll
        for (int c = 0; c < 8; ++c) A[k][c] *= pv;
        #pragma unroll
        for (int i = 0; i < 4; ++i) {
            if (i == k) continue;
            float f = A[i][k];
            #pragma unroll
            for (int c = 0; c < 8; ++c) A[i][c] -= f * A[k][c];
        }
    }
    // fused coefficients: out[m] = sum_n (Q[m][n] + hpost[m]*hpre[n]) x[n]
    float cf[16];
    #pragma unroll
    for (int m = 0; m < 4; ++m)
        #pragma unroll
        for (int n = 0; n < 4; ++n)
            cf[m * 4 + n] = A[m][4 + n] + hpost[m] * hpre[n];

    // Phase 3: outputs — lane covers 4 float4 positions per n-row (coalesced)
    const float* xt = x + (size_t)token * DTOT;
    float* ot = out + (size_t)token * DTOT;

    #pragma unroll
    for (int cc = 0; cc < 4; ++cc) {
        const int c0 = cc * 256 + lane * 4;
        float4 xv[4];
        #pragma unroll
        for (int n = 0; n < 4; ++n)
            xv[n] = *(const float4*)(xt + n * 1024 + c0);
        #pragma unroll
        for (int m = 0; m < 4; ++m) {
            float4 o;
            o.x = cf[m*4+0] * xv[0].x; o.y = cf[m*4+0] * xv[0].y;
            o.z = cf[m*4+0] * xv[0].z; o.w = cf[m*4+0] * xv[0].w;
            #pragma unroll
            for (int n = 1; n < 4; ++n) {
                const float c = cf[m * 4 + n];
                o.x += c * xv[n].x;
                o.y += c * xv[n].y;
                o.z += c * xv[n].z;
                o.w += c * xv[n].w;
            }
            *(float4*)(ot + m * 1024 + c0) = o;
        }
    }
}

// ---------------------------------------------------------------------------
extern "C" void kernel_launch(void* const* d_in, const int* in_sizes, int n_in,
                              void* d_out, int out_size, void* d_ws, size_t ws_size,
                              hipStream_t stream) {
    const float* x     = (const float*)d_in[0];
    const float* nw    = (const float*)d_in[1];
    const float* Wpre  = (const float*)d_in[2];
    const float* Wpost = (const float*)d_in[3];
    const float* Wres  = (const float*)d_in[4];
    const float* bpre  = (const float*)d_in[5];
    const float* bpost = (const float*)d_in[6];
    const float* bres  = (const float*)d_in[7];
    const float* apre  = (const float*)d_in[8];
    const float* apost = (const float*)d_in[9];
    const float* ares  = (const float*)d_in[10];
    float* out = (float*)d_out;

    // workspace: Wt (4096*24 fp32 = 384KB) | Gpart (16*25*16384 fp32 ~ 26.2MB)
    float* Wt    = (float*)d_ws;
    float* Gpart = (float*)((char*)d_ws + (size_t)DTOT * NJ * sizeof(float));

    prep_kernel<<<(DTOT * NJ + 255) / 256, 256, 0, stream>>>(Wpre, Wpost, Wres, nw, Wt);

    dim3 ga(NTOK / TOKB, NCHUNK);   // 64 x 16
    dots_kernel<<<ga, 256, 0, stream>>>(x, Wt, Gpart);

    out_kernel<<<NTOK / 4, 256, 0, stream>>>(x, Gpart, bpre, bpost, bres,
                                             apre, apost, ares, out);
}